// Round 8
// baseline (670.209 us; speedup 1.0000x reference)
//
#include <hip/hip_runtime.h>
#include <math.h>

#define B_     64
#define N_     128
#define S_     2048
#define D_     128
#define K_TOP  128
#define CAPB   2048           // per-block LDS candidate buffer (expected ~630)
#define SHCAP  (16 * CAPB)    // shared per-(batch,side) list: overflow impossible
#define SELCAP 2048           // theta-filtered select list (expected ~130)

typedef _Float16 f16x8 __attribute__((ext_vector_type(8)));
typedef float    f32x4 __attribute__((ext_vector_type(4)));

union Frag { uint4 u; f16x8 h; };

// Monotone mapping: float total order -> unsigned total order
__device__ __forceinline__ unsigned fkey(float x) {
    unsigned u = __float_as_uint(x);
    return (u & 0x80000000u) ? ~u : (u | 0x80000000u);
}
__device__ __forceinline__ float unkey(unsigned k) {
    unsigned u = (k & 0x80000000u) ? (k & 0x7fffffffu) : ~k;
    return __uint_as_float(u);
}

// 8 fp32 -> 8 fp16 (RNE) packed into uint4
__device__ __forceinline__ uint4 cvt8h(float4 a, float4 b) {
    union { _Float16 h[8]; uint4 u; } r;
    r.h[0] = (_Float16)a.x; r.h[1] = (_Float16)a.y;
    r.h[2] = (_Float16)a.z; r.h[3] = (_Float16)a.w;
    r.h[4] = (_Float16)b.x; r.h[5] = (_Float16)b.y;
    r.h[6] = (_Float16)b.z; r.h[7] = (_Float16)b.w;
    return r.u;
}

// ONE kernel: GEMM phase (identical to R4/R5, proven 77-80us, 0 conflicts)
// + per-(batch,side) finisher block runs the exact select + score + loss.
//
// Phase A proof: the 128 rowmaxes are 128 distinct elements of the block,
// so the block's 128th-largest >= min(rowmax) => {v >= min(rowmax)} is a
// superset of the block's top-128 (hence of block ∩ global top-128).
// Phase B proof: the 2048 segment maxes are distinct elements, so the
// global 128th-largest T >= s128 (128th-largest segmax) >= theta (its
// coarse-bin lower bound) => theta-filter preserves all of the top-128.
__global__ __launch_bounds__(256) void gemm_select(
    const float* __restrict__ q, const float* __restrict__ dpos,
    const float* __restrict__ dneg, int nb, int b0,
    unsigned* __restrict__ rowmaxLocal,   // [2nb*16*N_] segment maxes
    unsigned* __restrict__ cand,          // [2nb*SHCAP] shared lists
    unsigned* __restrict__ candCnt,       // [2nb] (pre-zeroed)
    unsigned* __restrict__ tick,          // [2nb] tickets (pre-zeroed)
    unsigned* __restrict__ ctr,           // loss ticket (pre-zeroed)
    float* __restrict__ sc, float* __restrict__ out)
{
    __shared__ uint4 sh4[2048];           // exactly 32 KiB; all scratch aliases it
    const int z  = blockIdx.z;
    const int bz = (z < nb) ? z : z - nb;
    const float* docs = (z < nb) ? dpos : dneg;
    const int bx = blockIdx.x;
    const int s0 = bx * 128;
    const float* qb = q + (size_t)(b0 + bz) * N_ * D_;
    const float* db = docs + (size_t)(b0 + bz) * S_ * D_;

    const int t    = threadIdx.x;
    const int lane = t & 63;
    const int w    = t >> 6;
    const int quad = lane >> 4;
    const int m    = lane & 15;
    const int Ibase = (w >> 1) << 2;
    const int Jbase = (w & 1) << 2;

    f32x4 acc[4][4];
    #pragma unroll
    for (int i = 0; i < 4; ++i)
        #pragma unroll
        for (int j = 0; j < 4; ++j)
            acc[i][j] = f32x4{0.f, 0.f, 0.f, 0.f};

    for (int k0 = 0; k0 < D_; k0 += 64) {
        // coalesced stage: ci -> row=ci>>3, oct=ci&7; XOR-swizzled LDS store
        #pragma unroll
        for (int p = 0; p < 4; ++p) {
            int ci  = t + p * 256;
            int row = ci >> 3;
            int oct = ci & 7;
            int idx = ((row >> 4) << 7) + (oct << 4) + ((row & 15) ^ oct);
            const float* ga = qb + (size_t)row * D_ + k0 + oct * 8;
            sh4[idx] = cvt8h(*(const float4*)ga, *(const float4*)(ga + 4));
            const float* gb = db + (size_t)(s0 + row) * D_ + k0 + oct * 8;
            sh4[1024 + idx] = cvt8h(*(const float4*)gb, *(const float4*)(gb + 4));
        }
        __syncthreads();
        #pragma unroll
        for (int ks = 0; ks < 2; ++ks) {
            const int oa = ks * 4 + quad;
            const int sw = (oa << 4) + (m ^ oa);
            Frag af[4], bf[4];
            #pragma unroll
            for (int i = 0; i < 4; ++i) {
                af[i].u = sh4[((Ibase + i) << 7) + sw];
                bf[i].u = sh4[1024 + ((Jbase + i) << 7) + sw];
            }
            #pragma unroll
            for (int i = 0; i < 4; ++i)
                #pragma unroll
                for (int j = 0; j < 4; ++j)
                    acc[i][j] = __builtin_amdgcn_mfma_f32_16x16x32_f16(
                        af[i].h, bf[j].h, acc[i][j], 0, 0, 0);
        }
        __syncthreads();
    }

    // ---- Phase A epilogue (scratch aliased into sh4 words) ----
    unsigned* W   = (unsigned*)sh4;
    unsigned* rmx = W;            // [0,128)
    unsigned* ctl = W + 128;      // [128]=minrm,[129]=cnt,[130]=base,[131]=fin
    unsigned* buf = W + 256;      // [256, 256+CAPB)
    if (t < 128) rmx[t] = 0u;
    if (t == 0) { ctl[0] = 0xFFFFFFFFu; ctl[1] = 0u; }
    __syncthreads();

    // per-row max (C/D layout: col = lane&15, row = quad*4 + reg)
    #pragma unroll
    for (int i = 0; i < 4; ++i) {
        #pragma unroll
        for (int r = 0; r < 4; ++r) {
            int row = ((Ibase + i) << 4) + (quad << 2) + r;
            unsigned km = max(max(fkey(acc[i][0][r]), fkey(acc[i][1][r])),
                              max(fkey(acc[i][2][r]), fkey(acc[i][3][r])));
            #pragma unroll
            for (int off = 1; off < 16; off <<= 1)
                km = max(km, (unsigned)__shfl_xor((int)km, off, 64));
            if (m == 0) atomicMax(&rmx[row], km);
        }
    }
    __syncthreads();

    const int slot = z * 16 + bx;
    if (t < 128) rowmaxLocal[(size_t)slot * N_ + t] = rmx[t];

    // min over the 128 row maxima
    unsigned mv = (t < 128) ? rmx[t] : 0xFFFFFFFFu;
    #pragma unroll
    for (int off = 32; off > 0; off >>= 1)
        mv = min(mv, (unsigned)__shfl_xor((int)mv, off, 64));
    if ((t & 63) == 0) atomicMin(&ctl[0], mv);
    __syncthreads();
    const unsigned minrm = ctl[0];

    // contention-free compaction: per-thread count -> wave prefix scan ->
    // one LDS atomicAdd per wave -> exclusive write positions
    unsigned cnt = 0;
    #pragma unroll
    for (int i = 0; i < 4; ++i)
        #pragma unroll
        for (int j = 0; j < 4; ++j)
            #pragma unroll
            for (int r = 0; r < 4; ++r)
                cnt += (fkey(acc[i][j][r]) >= minrm) ? 1u : 0u;

    unsigned incl = cnt;
    #pragma unroll
    for (int d = 1; d < 64; d <<= 1) {
        unsigned o = (unsigned)__shfl_up((int)incl, d, 64);
        if (lane >= d) incl += o;
    }
    unsigned base = 0;
    if (lane == 63) base = atomicAdd(&ctl[1], incl);   // incl@63 = wave total
    base = (unsigned)__shfl((int)base, 63, 64);
    unsigned pos = base + (incl - cnt);

    #pragma unroll
    for (int i = 0; i < 4; ++i)
        #pragma unroll
        for (int j = 0; j < 4; ++j)
            #pragma unroll
            for (int r = 0; r < 4; ++r) {
                unsigned u = fkey(acc[i][j][r]);
                if (u >= minrm) {
                    if (pos < CAPB) buf[pos] = u;
                    ++pos;
                }
            }
    __syncthreads();
    if (t == 0) ctl[2] = atomicAdd(&candCnt[z], min(ctl[1], (unsigned)CAPB));
    __syncthreads();
    {
        const unsigned c  = min(ctl[1], (unsigned)CAPB);
        const unsigned gb = ctl[2];
        unsigned* gdst = cand + (size_t)z * SHCAP;
        for (unsigned i = t; i < c; i += 256) {
            unsigned p2 = gb + i;
            if (p2 < SHCAP) gdst[p2] = buf[i];
        }
    }
    __syncthreads();                       // all block stores issued

    // ---- ticket: last-arriving block per (batch,side) becomes finisher ----
    __threadfence();                       // release: stores visible device-wide
    if (t == 0) {
        unsigned old = __hip_atomic_fetch_add(&tick[z], 1u, __ATOMIC_ACQ_REL,
                                              __HIP_MEMORY_SCOPE_AGENT);
        ctl[3] = (old == 15u) ? 1u : 0u;   // uniform for the whole block
    }
    __syncthreads();
    if (ctl[3] == 0u) return;              // non-finisher blocks exit (uniform)
    __threadfence();                       // acquire side of the handoff
    __syncthreads();                       // guard sh4 reuse vs ctl[3] reads

    // ---- Phase B (one block per (batch,side)): exact select + score ----
    // LDS word map (8192 words): seg/list [0,2048), hist [2048,6144),
    // scan [6144,6400), bctl [6400,6408), fred [6408,6416)
    unsigned* seg  = W;
    unsigned* hist = W + 2048;
    unsigned* scn  = W + 6144;
    unsigned* bctl = W + 6400;
    float*    fred = (float*)(W + 6408);

    const unsigned* rml = rowmaxLocal + (size_t)z * 16 * N_;
    for (int i = t; i < 2048; i += 256) seg[i] = rml[i];
    for (int i = t; i < 4096; i += 256) hist[i] = 0u;
    if (t == 0) bctl[1] = 0u;
    __syncthreads();

    // per-row max over the 16 slots (row = t for t < 128), kept in register
    unsigned myrm = 0u;
    if (t < N_) {
        #pragma unroll
        for (int s = 0; s < 16; ++s) myrm = max(myrm, seg[s * 128 + t]);
    }
    // coarse histogram of segmaxes (top 11 bits), 2 replicas
    {
        const unsigned rep = t & 1;
        for (int i = t; i < 2048; i += 256)
            atomicAdd(&hist[((seg[i] >> 21) << 1) | rep], 1u);
    }
    __syncthreads();
    {
        unsigned s = 0;
        #pragma unroll
        for (int j = 0; j < 8; ++j) {
            int bin = t * 8 + j;
            s += hist[bin * 2] + hist[bin * 2 + 1];
        }
        scn[t] = s;
    }
    __syncthreads();
    #pragma unroll
    for (int d = 1; d < 256; d <<= 1) {
        unsigned v2 = scn[t] + ((t + d < 256) ? scn[t + d] : 0u);
        __syncthreads();
        scn[t] = v2;
        __syncthreads();
    }
    {
        unsigned Sme = scn[t];
        unsigned Snx = (t == 255) ? 0u : scn[t + 1];
        if (Sme >= K_TOP && Snx < K_TOP) {
            unsigned cum = Snx;
            unsigned lbv = (unsigned)(t * 8);
            for (int bin = t * 8 + 7; bin >= t * 8; --bin) {
                unsigned hh = hist[bin * 2] + hist[bin * 2 + 1];
                if (cum + hh >= K_TOP) { lbv = (unsigned)bin; break; }
                cum += hh;
            }
            bctl[0] = lbv << 21;           // theta <= s128 <= T
        }
    }
    __syncthreads();
    const unsigned theta = bctl[0];

    // filter shared candidates >= theta into LDS list (~130 pass)
    unsigned* list = W;                    // reuse seg area (myrm in regs)
    const unsigned ccnt = min(
        __hip_atomic_load(&candCnt[z], __ATOMIC_ACQUIRE,
                          __HIP_MEMORY_SCOPE_AGENT),
        (unsigned)SHCAP);
    const unsigned* csrc = cand + (size_t)z * SHCAP;
    for (unsigned i = t; i < ccnt; i += 256) {
        unsigned u = csrc[i];
        if (u >= theta) {
            unsigned posx = atomicAdd(&bctl[1], 1u);
            if (posx < SELCAP) list[posx] = u;
        }
    }
    __syncthreads();
    const int total = (int)min(bctl[1], (unsigned)SELCAP);

    // exact radix-256 select, 4 rounds, 8 lane-replicas per bin
    if (t == 0) { bctl[2] = 0u; bctl[3] = (unsigned)K_TOP; }
    __syncthreads();
    for (int r = 0; r < 4; ++r) {
        const int shift = 24 - 8 * r;
        for (int i = t; i < 2048; i += 256) hist[i] = 0u;
        __syncthreads();
        const unsigned pref = bctl[2];
        const int k = (int)bctl[3];
        const unsigned pm = (r == 0) ? 0u : (0xFFFFFFFFu << (shift + 8));
        for (int i = t; i < total; i += 256) {
            unsigned u = list[i];
            if ((u & pm) == (pref & pm))
                atomicAdd(&hist[(((u >> shift) & 255u) << 3) | (t & 7)], 1u);
        }
        __syncthreads();
        unsigned hv = 0;
        #pragma unroll
        for (int j = 0; j < 8; ++j) hv += hist[(t << 3) | j];
        scn[t] = hv;
        __syncthreads();
        #pragma unroll
        for (int d = 1; d < 256; d <<= 1) {
            unsigned v2 = scn[t] + ((t + d < 256) ? scn[t + d] : 0u);
            __syncthreads();
            scn[t] = v2;
            __syncthreads();
        }
        unsigned Sme = scn[t];
        unsigned Snx = (t == 255) ? 0u : scn[t + 1];
        if (Sme >= (unsigned)k && Snx < (unsigned)k) {
            bctl[2] = pref | ((unsigned)t << shift);
            bctl[3] = (unsigned)(k - (int)Snx);
        }
        __syncthreads();
    }
    const unsigned T = bctl[2];

    // score from the 128 row maxima (reduce order identical to prior rounds)
    float v = 0.f, c = 0.f;
    if (t < N_ && myrm >= T) { v = fmaxf(unkey(myrm), 0.f); c = 1.f; }
    #pragma unroll
    for (int off = 32; off > 0; off >>= 1) {
        v += __shfl_xor(v, off, 64);
        c += __shfl_xor(c, off, 64);
    }
    const int wp = t >> 6;
    if ((t & 63) == 0) { fred[wp] = v; fred[4 + wp] = c; }
    __syncthreads();
    if (t == 0) {
        float Sv = fred[0] + fred[1] + fred[2] + fred[3];
        float Cv = fred[4] + fred[5] + fred[6] + fred[7];
        int b = b0 + ((z < nb) ? z : z - nb);
        int side = (z < nb) ? 0 : 1;
        float scv = Sv / fmaxf(Cv, 0.001f);
        __hip_atomic_store(&sc[side * B_ + b], scv, __ATOMIC_RELEASE,
                           __HIP_MEMORY_SCOPE_AGENT);
        unsigned old = __hip_atomic_fetch_add(ctr, 1u, __ATOMIC_ACQ_REL,
                                              __HIP_MEMORY_SCOPE_AGENT);
        bctl[4] = (old == 2u * B_ - 1u) ? 1u : 0u;
    }
    __syncthreads();
    // last finishing (batch,side) device-wide computes the loss
    if (bctl[4] != 0u && t < 64) {
        float pos = __hip_atomic_load(&sc[t], __ATOMIC_ACQUIRE,
                                      __HIP_MEMORY_SCOPE_AGENT);
        float neg = __hip_atomic_load(&sc[B_ + t], __ATOMIC_ACQUIRE,
                                      __HIP_MEMORY_SCOPE_AGENT);
        float x = neg - pos;
        float sp = (x > 20.f) ? x : log1pf(expf(x));
        #pragma unroll
        for (int o = 32; o > 0; o >>= 1) sp += __shfl_xor(sp, o, 64);
        if (t == 0) out[0] = sp * (1.f / B_);
    }
}

extern "C" void kernel_launch(void* const* d_in, const int* in_sizes, int n_in,
                              void* d_out, int out_size, void* d_ws, size_t ws_size,
                              hipStream_t stream) {
    const float* q    = (const float*)d_in[0];
    const float* dpos = (const float*)d_in[1];
    const float* dneg = (const float*)d_in[2];
    float* out = (float*)d_out;
    char* ws = (char*)d_ws;

    // per-batch bytes (x2 sides): rowmax 16*128*4 + shared cand SHCAP*4
    const size_t per_batch = 2ull * (16 * N_ + SHCAP) * 4;
    const size_t fixed = 512 + 256 + 512 + 512;
    size_t avail = (ws_size > fixed) ? (ws_size - fixed) : 0;
    int Bc = (int)(avail / per_batch);
    if (Bc > B_) Bc = B_;
    if (Bc < 1) Bc = 1;

    char* p = ws;
    float*    sc          = (float*)p;    p += 512;   // 2*B_ floats
    unsigned* ctr         = (unsigned*)p; p += 256;   // loss ticket
    unsigned* candCnt     = (unsigned*)p; p += 512;   // up to 128 counters
    unsigned* tick        = (unsigned*)p; p += 512;   // up to 128 tickets
    unsigned* rowmaxLocal = (unsigned*)p; p += (size_t)2 * Bc * 16 * N_ * 4;
    unsigned* cand        = (unsigned*)p; p += (size_t)2 * Bc * SHCAP * 4;

    // one memset covers ctr + candCnt + tick (contiguous)
    (void)hipMemsetAsync(ctr, 0, 256 + 512 + 512, stream);
    for (int b0 = 0; b0 < B_; b0 += Bc) {
        int nb = (B_ - b0 < Bc) ? (B_ - b0) : Bc;
        if (b0 > 0) (void)hipMemsetAsync(candCnt, 0, 1024, stream);
        gemm_select<<<dim3(S_ / 128, 1, 2 * nb), 256, 0, stream>>>(
            q, dpos, dneg, nb, b0, rowmaxLocal, cand, candCnt, tick, ctr, sc, out);
    }
}

// Round 9
// 206.240 us; speedup vs baseline: 3.2497x; 3.2497x over previous
//
#include <hip/hip_runtime.h>
#include <math.h>

#define B_     64
#define N_     128
#define S_     2048
#define D_     128
#define K_TOP  128
#define CAPB   2048           // per-block LDS candidate buffer (expected ~630)
#define SHCAP  (16 * CAPB)    // shared per-(batch,side) list: overflow impossible
#define SELCAP 3072           // theta-filtered select list (expected ~700)

typedef _Float16 f16x8 __attribute__((ext_vector_type(8)));
typedef float    f32x4 __attribute__((ext_vector_type(4)));

union Frag { uint4 u; f16x8 h; };

// Monotone mapping: float total order -> unsigned total order
__device__ __forceinline__ unsigned fkey(float x) {
    unsigned u = __float_as_uint(x);
    return (u & 0x80000000u) ? ~u : (u | 0x80000000u);
}
__device__ __forceinline__ float unkey(unsigned k) {
    unsigned u = (k & 0x80000000u) ? (k & 0x7fffffffu) : ~k;
    return __uint_as_float(u);
}

// 8 fp32 -> 8 fp16 (RNE) packed into uint4
__device__ __forceinline__ uint4 cvt8h(float4 a, float4 b) {
    union { _Float16 h[8]; uint4 u; } r;
    r.h[0] = (_Float16)a.x; r.h[1] = (_Float16)a.y;
    r.h[2] = (_Float16)a.z; r.h[3] = (_Float16)a.w;
    r.h[4] = (_Float16)b.x; r.h[5] = (_Float16)b.y;
    r.h[6] = (_Float16)b.z; r.h[7] = (_Float16)b.w;
    return r.u;
}

// K1: fp16 MFMA GEMM, 128x128 tile, BK=64, LDS-staged (R4/R5 structure,
// proven 79-80us, ~0 bank conflicts). NO device-scope fences (R8 lesson:
// per-block agent fences nuke L2 -> 7.5x slowdown); cross-kernel
// visibility comes from the kernel boundary.
// Epilogue proof: the 128 rowmaxes are 128 distinct elements of the block,
// so the block's 128th-largest >= min(rowmax) => {v >= min(rowmax)} is a
// superset of the block's top-128 (hence of block ∩ global top-128).
__global__ __launch_bounds__(256) void gemm_fused(
    const float* __restrict__ q, const float* __restrict__ dpos,
    const float* __restrict__ dneg, int nb, int b0,
    unsigned* __restrict__ rowmaxLocal,   // [2nb*16*N_] segment maxes
    unsigned* __restrict__ cand,          // [2nb*SHCAP] shared lists
    unsigned* __restrict__ candCnt)       // [2nb] (pre-zeroed)
{
    __shared__ uint4 sh4[2048];           // exactly 32 KiB
    const int z  = blockIdx.z;
    const int bz = (z < nb) ? z : z - nb;
    const float* docs = (z < nb) ? dpos : dneg;
    const int bx = blockIdx.x;
    const int s0 = bx * 128;
    const float* qb = q + (size_t)(b0 + bz) * N_ * D_;
    const float* db = docs + (size_t)(b0 + bz) * S_ * D_;

    const int t    = threadIdx.x;
    const int lane = t & 63;
    const int w    = t >> 6;
    const int quad = lane >> 4;
    const int m    = lane & 15;
    const int Ibase = (w >> 1) << 2;
    const int Jbase = (w & 1) << 2;

    f32x4 acc[4][4];
    #pragma unroll
    for (int i = 0; i < 4; ++i)
        #pragma unroll
        for (int j = 0; j < 4; ++j)
            acc[i][j] = f32x4{0.f, 0.f, 0.f, 0.f};

    for (int k0 = 0; k0 < D_; k0 += 64) {
        // coalesced stage: ci -> row=ci>>3, oct=ci&7; XOR-swizzled LDS store
        #pragma unroll
        for (int p = 0; p < 4; ++p) {
            int ci  = t + p * 256;
            int row = ci >> 3;
            int oct = ci & 7;
            int idx = ((row >> 4) << 7) + (oct << 4) + ((row & 15) ^ oct);
            const float* ga = qb + (size_t)row * D_ + k0 + oct * 8;
            sh4[idx] = cvt8h(*(const float4*)ga, *(const float4*)(ga + 4));
            const float* gb = db + (size_t)(s0 + row) * D_ + k0 + oct * 8;
            sh4[1024 + idx] = cvt8h(*(const float4*)gb, *(const float4*)(gb + 4));
        }
        __syncthreads();
        #pragma unroll
        for (int ks = 0; ks < 2; ++ks) {
            const int oa = ks * 4 + quad;
            const int sw = (oa << 4) + (m ^ oa);
            Frag af[4], bf[4];
            #pragma unroll
            for (int i = 0; i < 4; ++i) {
                af[i].u = sh4[((Ibase + i) << 7) + sw];
                bf[i].u = sh4[1024 + ((Jbase + i) << 7) + sw];
            }
            #pragma unroll
            for (int i = 0; i < 4; ++i)
                #pragma unroll
                for (int j = 0; j < 4; ++j)
                    acc[i][j] = __builtin_amdgcn_mfma_f32_16x16x32_f16(
                        af[i].h, bf[j].h, acc[i][j], 0, 0, 0);
        }
        __syncthreads();
    }

    // ---- epilogue scratch, aliased into sh4 (words) ----
    unsigned* rmx = (unsigned*)sh4;         // [0,128): row maxima
    unsigned* ctl = ((unsigned*)sh4) + 128; // [128]=minrm,[129]=cnt,[130]=base
    unsigned* buf = ((unsigned*)sh4) + 256; // [256, 256+CAPB)
    if (t < 128) rmx[t] = 0u;
    if (t == 0) { ctl[0] = 0xFFFFFFFFu; ctl[1] = 0u; }
    __syncthreads();

    // per-row max (C/D layout: col = lane&15, row = quad*4 + reg)
    #pragma unroll
    for (int i = 0; i < 4; ++i) {
        #pragma unroll
        for (int r = 0; r < 4; ++r) {
            int row = ((Ibase + i) << 4) + (quad << 2) + r;
            unsigned km = max(max(fkey(acc[i][0][r]), fkey(acc[i][1][r])),
                              max(fkey(acc[i][2][r]), fkey(acc[i][3][r])));
            #pragma unroll
            for (int off = 1; off < 16; off <<= 1)
                km = max(km, (unsigned)__shfl_xor((int)km, off, 64));
            if (m == 0) atomicMax(&rmx[row], km);
        }
    }
    __syncthreads();

    const int slot = z * 16 + bx;
    if (t < 128) rowmaxLocal[(size_t)slot * N_ + t] = rmx[t];

    // min over the 128 row maxima
    unsigned mv = (t < 128) ? rmx[t] : 0xFFFFFFFFu;
    #pragma unroll
    for (int off = 32; off > 0; off >>= 1)
        mv = min(mv, (unsigned)__shfl_xor((int)mv, off, 64));
    if ((t & 63) == 0) atomicMin(&ctl[0], mv);
    __syncthreads();
    const unsigned minrm = ctl[0];

    // contention-free compaction: per-thread count -> wave prefix scan ->
    // one LDS atomicAdd per wave -> exclusive write positions
    unsigned cnt = 0;
    #pragma unroll
    for (int i = 0; i < 4; ++i)
        #pragma unroll
        for (int j = 0; j < 4; ++j)
            #pragma unroll
            for (int r = 0; r < 4; ++r)
                cnt += (fkey(acc[i][j][r]) >= minrm) ? 1u : 0u;

    unsigned incl = cnt;
    #pragma unroll
    for (int d = 1; d < 64; d <<= 1) {
        unsigned o = (unsigned)__shfl_up((int)incl, d, 64);
        if (lane >= d) incl += o;
    }
    unsigned base = 0;
    if (lane == 63) base = atomicAdd(&ctl[1], incl);   // incl@63 = wave total
    base = (unsigned)__shfl((int)base, 63, 64);
    unsigned pos = base + (incl - cnt);

    #pragma unroll
    for (int i = 0; i < 4; ++i)
        #pragma unroll
        for (int j = 0; j < 4; ++j)
            #pragma unroll
            for (int r = 0; r < 4; ++r) {
                unsigned u = fkey(acc[i][j][r]);
                if (u >= minrm) {
                    if (pos < CAPB) buf[pos] = u;
                    ++pos;
                }
            }
    __syncthreads();
    // reserve a range in the shared (batch,side) list; coalesced copy-out
    if (t == 0) ctl[2] = atomicAdd(&candCnt[z], min(ctl[1], (unsigned)CAPB));
    __syncthreads();
    const unsigned c  = min(ctl[1], (unsigned)CAPB);
    const unsigned gb = ctl[2];
    unsigned* gdst = cand + (size_t)z * SHCAP;
    for (unsigned i = t; i < c; i += 256) {
        unsigned p2 = gb + i;
        if (p2 < SHCAP) gdst[p2] = buf[i];   // p2 < 16*CAPB always holds
    }
}

// K2: one block per (batch,side).
//  theta = min over rows of the GLOBAL rowmax. The 128 global rowmaxes are
//  128 distinct elements, so T (global 128th-largest) >= min of them.
//  Each global rowmax is a block rowmax in its slot => present in cand =>
//  the filtered list has >= 128 elements and contains all of the top-128.
//  Filter is a vectorized uint4 stream + wave prefix-scan append (~700
//  survivors); then exact 4-round radix-256; score; fused loss via ticket.
__global__ __launch_bounds__(256) void select_score(
    const unsigned* __restrict__ cand, const unsigned* __restrict__ candCnt,
    const unsigned* __restrict__ rowmaxLocal, float* __restrict__ sc,
    unsigned* __restrict__ ctr, float* __restrict__ out, int nb, int b0)
{
    __shared__ unsigned list[SELCAP];     // 12 KiB
    __shared__ unsigned hist[2048];       // 256 bins x 8 replicas
    __shared__ unsigned wtot[4];
    __shared__ unsigned sctl[4];          // [0]=theta,[1]=count,[2]=pref,[3]=k
    __shared__ float fred[8];
    __shared__ unsigned sdone;

    const int z    = blockIdx.x;
    const int tid  = threadIdx.x;
    const int lane = tid & 63;
    const int wp   = tid >> 6;

    if (tid == 0) { sctl[0] = 0xFFFFFFFFu; sctl[1] = 0u; }
    __syncthreads();

    // global rowmax per row (strided loads) + theta = min over rows
    unsigned myrm = 0u;
    if (tid < N_) {
        const unsigned* rml = rowmaxLocal + (size_t)z * 16 * N_ + tid;
        #pragma unroll
        for (int s = 0; s < 16; ++s) myrm = max(myrm, rml[s * N_]);
    }
    unsigned mv = (tid < N_) ? myrm : 0xFFFFFFFFu;
    #pragma unroll
    for (int off = 32; off > 0; off >>= 1)
        mv = min(mv, (unsigned)__shfl_xor((int)mv, off, 64));
    if ((tid & 63) == 0) atomicMin(&sctl[0], mv);
    __syncthreads();
    const unsigned theta = sctl[0];

    // vectorized filter: uint4 stream, wave prefix-scan append
    const unsigned ccnt = min(candCnt[z], (unsigned)SHCAP);
    const uint4* csrc4 = (const uint4*)(cand + (size_t)z * SHCAP);
    const unsigned n4 = (ccnt + 3u) >> 2;
    for (unsigned i0 = 0; i0 < n4; i0 += 256) {
        const unsigned i = i0 + tid;
        unsigned uv[4];
        bool pr[4];
        unsigned c = 0;
        uint4 u4 = make_uint4(0u, 0u, 0u, 0u);
        if (i < n4) u4 = csrc4[i];
        uv[0] = u4.x; uv[1] = u4.y; uv[2] = u4.z; uv[3] = u4.w;
        #pragma unroll
        for (int e = 0; e < 4; ++e) {
            pr[e] = (i < n4) && ((i << 2) + e < ccnt) && (uv[e] >= theta);
            c += pr[e] ? 1u : 0u;
        }
        unsigned incl = c;
        #pragma unroll
        for (int d = 1; d < 64; d <<= 1) {
            unsigned o = (unsigned)__shfl_up((int)incl, d, 64);
            if (lane >= d) incl += o;
        }
        unsigned base = 0;
        if (lane == 63) base = atomicAdd(&sctl[1], incl);
        base = (unsigned)__shfl((int)base, 63, 64);
        unsigned pos = base + (incl - c);
        #pragma unroll
        for (int e = 0; e < 4; ++e)
            if (pr[e]) {
                if (pos < SELCAP) list[pos] = uv[e];
                ++pos;
            }
    }
    __syncthreads();
    const int total = (int)min(sctl[1], (unsigned)SELCAP);
    if (tid == 0) { sctl[2] = 0u; sctl[3] = (unsigned)K_TOP; }

    // exact radix-256 select, 4 rounds, 8 lane-replicas per bin,
    // warp shfl_down suffix scan (no Hillis-Steele barriers)
    for (int r = 0; r < 4; ++r) {
        const int shift = 24 - 8 * r;
        for (int i = tid; i < 2048; i += 256) hist[i] = 0u;
        __syncthreads();
        const unsigned pref = sctl[2];
        const unsigned k    = sctl[3];
        const unsigned pm = (r == 0) ? 0u : (0xFFFFFFFFu << (shift + 8));
        for (int i = tid; i < total; i += 256) {
            unsigned u = list[i];
            if ((u & pm) == (pref & pm))
                atomicAdd(&hist[(((u >> shift) & 255u) << 3) | (tid & 7)], 1u);
        }
        __syncthreads();
        unsigned hv = 0;
        #pragma unroll
        for (int j = 0; j < 8; ++j) hv += hist[(tid << 3) | j];
        unsigned v = hv;
        #pragma unroll
        for (int d = 1; d < 64; d <<= 1) {
            unsigned o = (unsigned)__shfl_down((int)v, d, 64);
            if (lane + d < 64) v += o;
        }
        if (lane == 0) wtot[wp] = v;      // warp total
        __syncthreads();
        unsigned add = 0;
        #pragma unroll
        for (int w2 = 0; w2 < 4; ++w2)
            if (w2 > wp) add += wtot[w2];
        unsigned Sme = v + add;           // suffix sum including bin tid
        unsigned Snx = Sme - hv;          // suffix excluding bin tid
        if (Sme >= k && Snx < k) {
            sctl[2] = pref | ((unsigned)tid << shift);
            sctl[3] = k - Snx;
        }
        __syncthreads();
    }
    const unsigned T = sctl[2];

    // score from the 128 row maxima (reduce order identical to prior rounds)
    float v = 0.f, c = 0.f;
    if (tid < N_ && myrm >= T) { v = fmaxf(unkey(myrm), 0.f); c = 1.f; }
    #pragma unroll
    for (int off = 32; off > 0; off >>= 1) {
        v += __shfl_xor(v, off, 64);
        c += __shfl_xor(c, off, 64);
    }
    if ((tid & 63) == 0) { fred[wp] = v; fred[4 + wp] = c; }
    __syncthreads();
    if (tid == 0) {
        float Sv = fred[0] + fred[1] + fred[2] + fred[3];
        float Cv = fred[4] + fred[5] + fred[6] + fred[7];
        int b = b0 + ((z < nb) ? z : z - nb);
        int side = (z < nb) ? 0 : 1;
        float scv = Sv / fmaxf(Cv, 0.001f);
        __hip_atomic_store(&sc[side * B_ + b], scv, __ATOMIC_RELEASE,
                           __HIP_MEMORY_SCOPE_AGENT);
        unsigned old = __hip_atomic_fetch_add(ctr, 1u, __ATOMIC_ACQ_REL,
                                              __HIP_MEMORY_SCOPE_AGENT);
        sdone = (old == 2u * B_ - 1u) ? 1u : 0u;
    }
    __syncthreads();
    // last finishing block (device-wide) computes the loss
    if (sdone != 0u && tid < 64) {
        float pos = __hip_atomic_load(&sc[tid], __ATOMIC_ACQUIRE,
                                      __HIP_MEMORY_SCOPE_AGENT);
        float neg = __hip_atomic_load(&sc[B_ + tid], __ATOMIC_ACQUIRE,
                                      __HIP_MEMORY_SCOPE_AGENT);
        float x = neg - pos;
        float sp = (x > 20.f) ? x : log1pf(expf(x));
        #pragma unroll
        for (int o = 32; o > 0; o >>= 1) sp += __shfl_xor(sp, o, 64);
        if (tid == 0) out[0] = sp * (1.f / B_);
    }
}

extern "C" void kernel_launch(void* const* d_in, const int* in_sizes, int n_in,
                              void* d_out, int out_size, void* d_ws, size_t ws_size,
                              hipStream_t stream) {
    const float* q    = (const float*)d_in[0];
    const float* dpos = (const float*)d_in[1];
    const float* dneg = (const float*)d_in[2];
    float* out = (float*)d_out;
    char* ws = (char*)d_ws;

    // per-batch bytes (x2 sides): rowmax 16*128*4 + shared cand SHCAP*4
    const size_t per_batch = 2ull * (16 * N_ + SHCAP) * 4;
    const size_t fixed = 512 + 256 + 512;
    size_t avail = (ws_size > fixed) ? (ws_size - fixed) : 0;
    int Bc = (int)(avail / per_batch);
    if (Bc > B_) Bc = B_;
    if (Bc < 1) Bc = 1;

    char* p = ws;
    float*    sc          = (float*)p;    p += 512;   // 2*B_ floats
    unsigned* ctr         = (unsigned*)p; p += 256;   // loss ticket
    unsigned* candCnt     = (unsigned*)p; p += 512;   // up to 128 counters
    unsigned* rowmaxLocal = (unsigned*)p; p += (size_t)2 * Bc * 16 * N_ * 4;
    unsigned* cand        = (unsigned*)p; p += (size_t)2 * Bc * SHCAP * 4;

    // one memset covers ctr + candCnt (contiguous)
    (void)hipMemsetAsync(ctr, 0, 256 + 512, stream);
    for (int b0 = 0; b0 < B_; b0 += Bc) {
        int nb = (B_ - b0 < Bc) ? (B_ - b0) : Bc;
        if (b0 > 0) (void)hipMemsetAsync(candCnt, 0, 512, stream);
        gemm_fused<<<dim3(S_ / 128, 1, 2 * nb), 256, 0, stream>>>(
            q, dpos, dneg, nb, b0, rowmaxLocal, cand, candCnt);
        select_score<<<2 * nb, 256, 0, stream>>>(
            cand, candCnt, rowmaxLocal, sc, ctr, out, nb, b0);
    }
}